// Round 1
// baseline (303.799 us; speedup 1.0000x reference)
//
#include <hip/hip_runtime.h>

// LSTM, B=4096 indep. sequences, T=2048 sequential steps, IN=3, H=4.
// Layout: 16 lanes per batch element. lane l in [0,16): gate row l of the
// PyTorch [4H, *] weight layout (rows 0-3 = i, 4-7 = f, 8-11 = g, 12-15 = o;
// unit u = l&3). 4 groups per wave, 4 waves per block (256 thr), 256 blocks
// -> 1024 waves = 1 wave/SIMD chip-wide. Latency-bound on the recurrence.

static constexpr int T_STEPS = 2048;
static constexpr int CHUNK   = 16;              // timesteps staged per load round
static constexpr int NCHUNK  = T_STEPS / CHUNK; // 128

// ds_swizzle BitMode: dst[l] = src[((l & and) | or) ^ xor],
// offset = (xor<<10) | (or<<5) | and  (per 32-lane half).
template<int OFF>
__device__ __forceinline__ float swz(float v) {
    return __int_as_float(__builtin_amdgcn_ds_swizzle(__float_as_int(v), OFF));
}

struct LState { float hb0, hb1, hb2, hb3, c; };

template<int TT>
__device__ __forceinline__ void lstm_step(
    const float (&xs)[3], LState& s,
    float wih0, float wih1, float wih2,
    float whh0, float whh1, float whh2, float whh3,
    float m, float Aa, float Bb)
{
    // x broadcast: component c of step TT sits at flat index 3*TT+c within the
    // 48-float chunk: register (idx>>4), source lane (idx&15). All static.
    constexpr int i0 = 3*TT + 0, i1 = 3*TT + 1, i2 = 3*TT + 2;
    float x0 = swz<((((i0 & 15) << 5) | 0x10))>(xs[i0 >> 4]);
    float x1 = swz<((((i1 & 15) << 5) | 0x10))>(xs[i1 >> 4]);
    float x2 = swz<((((i2 & 15) << 5) | 0x10))>(xs[i2 >> 4]);
    float xp = fmaf(x0, wih0, fmaf(x1, wih1, x2 * wih2));   // off critical path

    // gate preactivation: xp + sum_u h_u * w_hh[l][u]  (shallow FMA tree)
    float ga = fmaf(s.hb1, whh1, fmaf(s.hb0, whh0, xp));
    float gb = fmaf(s.hb2, whh2, s.hb3 * whh3);
    float gp = ga + gb;

    // unified activation: sigmoid lanes (i,f,o): 1/(1+2^(-1.4427x))
    //                     tanh lanes (g):        2/(1+2^(-2.8854x)) - 1
    float e   = exp2f(m * gp);
    float r   = __builtin_amdgcn_rcpf(1.0f + e);
    float act = fmaf(Aa, r, Bb);

    // gather f,g,o into the i-lanes (lanes 0-3 hold unit u = lane)
    float f = swz<0x101F>(act);   // lane ^ 4
    float g = swz<0x201F>(act);   // lane ^ 8
    float o = swz<0x301F>(act);   // lane ^ 12

    // c update (architecturally live in lanes 0-3 only; others compute junk)
    float cn = fmaf(f, s.c, act * g);   // act == i in lanes 0-3
    s.c = cn;

    float e2 = exp2f(-2.885390081777927f * cn);
    float th = fmaf(2.0f, __builtin_amdgcn_rcpf(1.0f + e2), -1.0f);
    float h  = o * th;

    // broadcast h0..h3 (lanes 0-3) to all 16 lanes of the group
    s.hb0 = swz<0x10>(h);
    s.hb1 = swz<0x30>(h);
    s.hb2 = swz<0x50>(h);
    s.hb3 = swz<0x70>(h);
}

template<int TT>
__device__ __forceinline__ void lstm_chunk(
    const float (&xs)[3], LState& s,
    float wih0, float wih1, float wih2,
    float whh0, float whh1, float whh2, float whh3,
    float m, float Aa, float Bb)
{
    lstm_step<TT>(xs, s, wih0, wih1, wih2, whh0, whh1, whh2, whh3, m, Aa, Bb);
    if constexpr (TT + 1 < CHUNK)
        lstm_chunk<TT + 1>(xs, s, wih0, wih1, wih2, whh0, whh1, whh2, whh3, m, Aa, Bb);
}

__global__ __launch_bounds__(256, 1) void lstm_kernel(
    const float* __restrict__ x,
    const float* __restrict__ w_ih,
    const float* __restrict__ w_hh,
    const float* __restrict__ fc_w,
    const float* __restrict__ fc_b,
    float* __restrict__ out)
{
    const int tid = threadIdx.x;
    const int l16 = tid & 15;            // lane within group == gate row
    const int grp = tid >> 4;            // group within block (0..15)
    const int b   = blockIdx.x * 16 + grp;
    const int gt  = l16 >> 2;            // 0=i 1=f 2=g 3=o

    // per-lane weights (uniform across groups)
    const float wih0 = w_ih[l16 * 3 + 0];
    const float wih1 = w_ih[l16 * 3 + 1];
    const float wih2 = w_ih[l16 * 3 + 2];
    const float whh0 = w_hh[l16 * 4 + 0];
    const float whh1 = w_hh[l16 * 4 + 1];
    const float whh2 = w_hh[l16 * 4 + 2];
    const float whh3 = w_hh[l16 * 4 + 3];

    const bool  is_g = (gt == 2);
    const float m  = is_g ? -2.885390081777927f : -1.4426950408889634f;
    const float Aa = is_g ? 2.0f : 1.0f;
    const float Bb = is_g ? -1.0f : 0.0f;

    const float* xb = x + (size_t)b * (T_STEPS * 3);

    LState s{0.f, 0.f, 0.f, 0.f, 0.f};

    // stage chunk 0 (48 consecutive floats = 16 timesteps), coalesced per group
    float xs[3];
    xs[0] = xb[l16];
    xs[1] = xb[l16 + 16];
    xs[2] = xb[l16 + 32];

    for (int chunk = 0; chunk < NCHUNK; ++chunk) {
        // prefetch next chunk (issued before the 16-step chain; compiler
        // schedules the vmem wait at the xs[] copy below)
        float nxs[3];
        const int nc = (chunk + 1 < NCHUNK) ? (chunk + 1) : (NCHUNK - 1);
        const float* p = xb + nc * 48;
        nxs[0] = p[l16];
        nxs[1] = p[l16 + 16];
        nxs[2] = p[l16 + 32];

        lstm_chunk<0>(xs, s, wih0, wih1, wih2, whh0, whh1, whh2, whh3, m, Aa, Bb);

        xs[0] = nxs[0]; xs[1] = nxs[1]; xs[2] = nxs[2];
    }

    if (l16 == 0) {
        const float fw0 = fc_w[0], fw1 = fc_w[1], fw2 = fc_w[2], fw3 = fc_w[3];
        const float fcb = fc_b[0];
        float r = fmaf(s.hb0, fw0,
                  fmaf(s.hb1, fw1,
                  fmaf(s.hb2, fw2,
                  fmaf(s.hb3, fw3, fcb))));
        out[b] = r;
    }
}

extern "C" void kernel_launch(void* const* d_in, const int* in_sizes, int n_in,
                              void* d_out, int out_size, void* d_ws, size_t ws_size,
                              hipStream_t stream) {
    const float* x    = (const float*)d_in[0];
    const float* w_ih = (const float*)d_in[1];
    const float* w_hh = (const float*)d_in[2];
    const float* fc_w = (const float*)d_in[3];
    const float* fc_b = (const float*)d_in[4];
    float* out = (float*)d_out;

    dim3 grid(4096 / 16);   // 256 blocks -> 1 per CU
    dim3 block(256);        // 4 waves -> 1 wave per SIMD
    hipLaunchKernelGGL(lstm_kernel, grid, block, 0, stream,
                       x, w_ih, w_hh, fc_w, fc_b, out);
}

// Round 2
// 204.871 us; speedup vs baseline: 1.4829x; 1.4829x over previous
//
#include <hip/hip_runtime.h>

// LSTM, B=4096, T=2048, IN=3, H=4. 16 lanes per batch element.
// lane l = 4q + j within its 16-lane group: gate row l (q = gate 0..3 = i,f,g,o;
// j = unit 0..3). Every lane computes the FULL c/h recurrence for unit j
// (quads are redundant replicas), so all cross-lane traffic is DPP (VALU pipe,
// ~4cy) instead of ds_swizzle (~120cy at 1 wave/SIMD). 256 blocks x 256 thr
// -> 1024 waves = 1 wave/SIMD chip-wide; pure latency-bound on the chain.

static constexpr int T_STEPS = 2048;
static constexpr int CHUNK   = 16;              // timesteps per x-staging chunk
static constexpr int NCHUNK  = T_STEPS / CHUNK; // 128

template<int CTRL>
__device__ __forceinline__ float dpp_f(float v) {
    return __int_as_float(__builtin_amdgcn_update_dpp(
        0, __float_as_int(v), CTRL, 0xF, 0xF, false));
}

struct Ctx {
    float wih0, wih1, wih2;
    float whh0, whh1, whh2, whh3;
    float m, Aa, Bb;      // unified activation constants (sigmoid vs tanh lanes)
    bool  b0, b1fo;       // per-lane gate-quadrant select bits (b1fo absorbs DPP dir)
};

template<int J>
__device__ __forceinline__ float comp(const float4& v) {
    if constexpr (J == 0) return v.x;
    else if constexpr (J == 1) return v.y;
    else if constexpr (J == 2) return v.z;
    else return v.w;
}

// x-projection for step TT of a chunk: xp = w_ih . x_t  (off the critical path)
template<int TT>
__device__ __forceinline__ void projx_t(float (&xp)[CHUNK], const float4 (&bf)[12],
                                        const Ctx& k) {
    constexpr int j0 = 3 * TT, j1 = j0 + 1, j2 = j0 + 2;
    float x0 = comp<(j0 & 3)>(bf[j0 >> 2]);
    float x1 = comp<(j1 & 3)>(bf[j1 >> 2]);
    float x2 = comp<(j2 & 3)>(bf[j2 >> 2]);
    xp[TT] = fmaf(x0, k.wih0, fmaf(x1, k.wih1, x2 * k.wih2));
    if constexpr (TT + 1 < CHUNK) projx_t<TT + 1>(xp, bf, k);
}

__device__ __forceinline__ void lstm_step(float xp, float& h, float& c, const Ctx& k) {
    // h0..h3 live in every quad (lane 4m+j holds h_j) -> quad_perm broadcasts
    float hb0 = dpp_f<0x00>(h);   // quad_perm [0,0,0,0]
    float hb1 = dpp_f<0x55>(h);   // [1,1,1,1]
    float hb2 = dpp_f<0xAA>(h);   // [2,2,2,2]
    float hb3 = dpp_f<0xFF>(h);   // [3,3,3,3]

    // own-gate preactivation for unit j (correct in ALL lanes)
    float p0 = fmaf(hb1, k.whh1, fmaf(hb0, k.whh0, xp));
    float p1 = fmaf(hb2, k.whh2, hb3 * k.whh3);
    float gp = p0 + p1;

    // unified activation: sigmoid (i,f,o lanes) / tanh (g lanes)
    float e   = __builtin_amdgcn_exp2f(k.m * gp);
    float act = fmaf(k.Aa, __builtin_amdgcn_rcpf(1.0f + e), k.Bb);

    // same-unit other-gate gather via row rotations (VALU-pipe DPP)
    float t1 = dpp_f<0x124>(act);   // row_ror:4
    float t2 = dpp_f<0x128>(act);   // row_ror:8
    float t3 = dpp_f<0x12C>(act);   // row_ror:12
    // cyclic (act,t1,t2,t3) -> (i,f,g,o) per gate-quadrant q:
    // i*g is direction-invariant: (q&1) ? t1*t3 : act*t2
    float prod = k.b0 ? t1 * t3 : act * t2;
    float A  = k.b0 ? t2  : t1;
    float Bv = k.b0 ? act : t3;
    float f  = k.b1fo ? A : Bv;     // b1fo = (q&2) ^ dirB  (probe-corrected)
    float o  = k.b1fo ? Bv : A;

    float cn = fmaf(f, c, prod);
    c = cn;
    float e2 = __builtin_amdgcn_exp2f(-2.885390081777927f * cn);
    float th = fmaf(2.0f, __builtin_amdgcn_rcpf(1.0f + e2), -1.0f);
    h = o * th;
}

template<int TT>
__device__ __forceinline__ void steps16(const float (&xp)[CHUNK], float& h, float& c,
                                        const Ctx& k) {
    lstm_step(xp[TT], h, c, k);
    if constexpr (TT + 1 < CHUNK) steps16<TT + 1>(xp, h, c, k);
}

__device__ __forceinline__ void loadbf(float4 (&bf)[12], const float4* p) {
    #pragma unroll
    for (int i = 0; i < 12; ++i) bf[i] = p[i];
}

__global__ __launch_bounds__(256, 1) void lstm_kernel(
    const float* __restrict__ x,
    const float* __restrict__ w_ih,
    const float* __restrict__ w_hh,
    const float* __restrict__ fc_w,
    const float* __restrict__ fc_b,
    float* __restrict__ out)
{
    const int tid = threadIdx.x;
    const int l16 = tid & 15;
    const int b   = blockIdx.x * 16 + (tid >> 4);
    const int gt  = l16 >> 2;     // gate quadrant q: 0=i 1=f 2=g 3=o

    Ctx k;
    k.wih0 = w_ih[l16 * 3 + 0];
    k.wih1 = w_ih[l16 * 3 + 1];
    k.wih2 = w_ih[l16 * 3 + 2];
    k.whh0 = w_hh[l16 * 4 + 0];
    k.whh1 = w_hh[l16 * 4 + 1];
    k.whh2 = w_hh[l16 * 4 + 2];
    k.whh3 = w_hh[l16 * 4 + 3];
    const bool is_g = (gt == 2);
    k.m  = is_g ? -2.885390081777927f : -1.4426950408889634f;
    k.Aa = is_g ? 2.0f : 1.0f;
    k.Bb = is_g ? -1.0f : 0.0f;
    k.b0 = (gt & 1) != 0;

    // Runtime probe for row_ror direction (A: dst[n]=src[(n-4)&15], B: src[(n+4)&15]).
    // Under B the f/o assignments swap, which is exactly b1 -> !b1 in the mux.
    {
        float probe = (float)l16;
        float t1p = dpp_f<0x124>(probe);
        bool dirB = (t1p == (float)((l16 + 4) & 15));
        k.b1fo = (((gt & 2) != 0) != dirB);
    }

    const float4* xb4 = reinterpret_cast<const float4*>(x + (size_t)b * (T_STEPS * 3));

    float4 bfA[12], bfB[12];        // double-buffered raw x (48 floats = 16 steps)
    float  xpA[CHUNK], xpB[CHUNK];  // double-buffered projections
    loadbf(bfA, xb4);
    loadbf(bfB, xb4 + 12);
    projx_t<0>(xpA, bfA, k);        // chunk 0 projections

    float h = 0.f, c = 0.f;

    for (int it = 0; it < NCHUNK / 2; ++it) {
        // chunk 2it: consume xpA; prefetch chunk 2it+2; project chunk 2it+1
        const int ca = (2 * it + 2 < NCHUNK) ? 2 * it + 2 : NCHUNK - 1;
        loadbf(bfA, xb4 + ca * 12);
        projx_t<0>(xpB, bfB, k);
        steps16<0>(xpA, h, c, k);
        // chunk 2it+1: consume xpB; prefetch chunk 2it+3; project chunk 2it+2
        const int cb = (2 * it + 3 < NCHUNK) ? 2 * it + 3 : NCHUNK - 1;
        loadbf(bfB, xb4 + cb * 12);
        projx_t<0>(xpA, bfA, k);
        steps16<0>(xpB, h, c, k);
    }

    // out[b] = fc_w . h + fc_b ; every lane holds h(unit l&3) -> quad reduce
    float r = h * fc_w[l16 & 3];
    r += dpp_f<0xB1>(r);   // quad_perm [1,0,3,2]
    r += dpp_f<0x4E>(r);   // quad_perm [2,3,0,1]
    if (l16 == 0) out[b] = r + fc_b[0];
}

extern "C" void kernel_launch(void* const* d_in, const int* in_sizes, int n_in,
                              void* d_out, int out_size, void* d_ws, size_t ws_size,
                              hipStream_t stream) {
    const float* x    = (const float*)d_in[0];
    const float* w_ih = (const float*)d_in[1];
    const float* w_hh = (const float*)d_in[2];
    const float* fc_w = (const float*)d_in[3];
    const float* fc_b = (const float*)d_in[4];
    float* out = (float*)d_out;

    dim3 grid(4096 / 16);   // 256 blocks -> 1 per CU
    dim3 block(256);        // 4 waves -> 1 wave per SIMD
    hipLaunchKernelGGL(lstm_kernel, grid, block, 0, stream,
                       x, w_ih, w_hh, fc_w, fc_b, out);
}